// Round 5
// baseline (8814.068 us; speedup 1.0000x reference)
//
#include <hip/hip_runtime.h>
#include <hip/hip_bf16.h>

using bf16 = __hip_bfloat16;
typedef __bf16 bf16x8 __attribute__((ext_vector_type(8)));
typedef float f32x4 __attribute__((ext_vector_type(4)));

#define N_CELLS 3000
#define N_GENES 1000
#define M_NODES 4000
#define NP 3072
#define MP 4096
#define SR 512       // E-stripe rows
#define CHMAX 1024   // GEMM1 output-chunk columns

// dual-mode scalar read: inputs are f32 (expected) or bf16 (hedge), sniffed.
__device__ __forceinline__ float rdv(const void* p, size_t i, int isbf) {
    if (isbf) return (float)((const bf16*)p)[i];
    return ((const float*)p)[i];
}

// X ~ U[0,1): as bf16 every word's low16 < 0x3F80 (~100%); as f32 ~25%.
__global__ void sniff_dtype(const unsigned int* __restrict__ X, int* __restrict__ flag)
{
    __shared__ int cnt[4];
    int t = threadIdx.x;
    int c = 0;
    for (int i = t; i < 2048; i += 256)
        if ((X[i] & 0xFFFFu) < 0x3F80u) c++;
    #pragma unroll
    for (int off = 32; off > 0; off >>= 1) c += __shfl_down(c, off);
    if ((t & 63) == 0) cnt[t >> 6] = c;
    __syncthreads();
    if (t == 0) flag[0] = (cnt[0] + cnt[1] + cnt[2] + cnt[3] > 1536) ? 1 : 0;
}

// ---------------------------------------------------------------------------
// NT GEMM: C[i,j] = sum_k A[i,k]*B[j,k], 128x128 tile, K%32==0, bf16 in,
// OutT out. RELU_BIAS: C=relu(C+bias[j]). TRANS_OUT: store C[j,i].
// SCALE_ROW: *rowinv[gi]. gi = iOff + tile row (A indexed locally).
// ---------------------------------------------------------------------------
template<bool RELU_BIAS, bool TRANS_OUT, bool SCALE_ROW, typename OutT>
__global__ __launch_bounds__(256, 2)
void gemm_nt(const bf16* __restrict__ A, int lda,
             const bf16* __restrict__ B, int ldb,
             const bf16* __restrict__ bias,
             const float* __restrict__ rowinv,
             OutT* __restrict__ C, int ldc,
             int K, int mBound, int nBound, int iOff)
{
    __shared__ __align__(16) bf16 As[128 * 32];
    __shared__ __align__(16) bf16 Bs[128 * 32];
    const int tid  = threadIdx.x;
    const int wave = tid >> 6;
    const int lane = tid & 63;
    const int i0 = blockIdx.y * 128;
    const int j0 = blockIdx.x * 128;

    const int r0 = tid >> 2;
    const int r1 = r0 + 64;
    const int kc = (tid & 3) * 8;
    const bf16* gA0 = A + (size_t)(i0 + r0) * lda + kc;
    const bf16* gA1 = A + (size_t)(i0 + r1) * lda + kc;
    const bf16* gB0 = B + (size_t)(j0 + r0) * ldb + kc;
    const bf16* gB1 = B + (size_t)(j0 + r1) * ldb + kc;

    const int wm = (wave >> 1) * 64;
    const int wn = (wave & 1) * 64;
    const int fr = lane & 15;
    const int fk = (lane >> 4) * 8;

    f32x4 acc[4][4] = {};

    for (int kt = 0; kt < K; kt += 32) {
        bf16x8 a0 = *(const bf16x8*)(gA0 + kt);
        bf16x8 a1 = *(const bf16x8*)(gA1 + kt);
        bf16x8 b0 = *(const bf16x8*)(gB0 + kt);
        bf16x8 b1 = *(const bf16x8*)(gB1 + kt);
        __syncthreads();
        *(bf16x8*)&As[r0 * 32 + kc] = a0;
        *(bf16x8*)&As[r1 * 32 + kc] = a1;
        *(bf16x8*)&Bs[r0 * 32 + kc] = b0;
        *(bf16x8*)&Bs[r1 * 32 + kc] = b1;
        __syncthreads();

        bf16x8 af[4], bfv[4];
        #pragma unroll
        for (int t = 0; t < 4; t++) {
            af[t]  = *(const bf16x8*)&As[(wm + t * 16 + fr) * 32 + fk];
            bfv[t] = *(const bf16x8*)&Bs[(wn + t * 16 + fr) * 32 + fk];
        }
        #pragma unroll
        for (int mt = 0; mt < 4; mt++)
            #pragma unroll
            for (int nt = 0; nt < 4; nt++)
                acc[mt][nt] = __builtin_amdgcn_mfma_f32_16x16x32_bf16(
                    af[mt], bfv[nt], acc[mt][nt], 0, 0, 0);
    }

    // C/D mapping: col(n)=lane&15, row(m)=(lane>>4)*4+reg
    const int ci = (lane >> 4) * 4;
    const int cj = lane & 15;
    #pragma unroll
    for (int nt = 0; nt < 4; nt++) {
        const int gj = j0 + wn + nt * 16 + cj;
        if (gj >= nBound) continue;
        float bv = 0.f;
        if (RELU_BIAS) bv = (float)bias[gj];
        #pragma unroll
        for (int mt = 0; mt < 4; mt++) {
            #pragma unroll
            for (int rg = 0; rg < 4; rg++) {
                const int gi = iOff + i0 + wm + mt * 16 + ci + rg;
                if (gi < mBound) {
                    float v = acc[mt][nt][rg];
                    if (RELU_BIAS) { v += bv; v = v > 0.f ? v : 0.f; }
                    if (SCALE_ROW) v *= rowinv[gi];
                    if (TRANS_OUT) C[(size_t)gj * ldc + gi] = (OutT)v;
                    else           C[(size_t)gi * ldc + gj] = (OutT)v;
                }
            }
        }
    }
}

// ---------------------------------------------------------------------------
// Layer-0 NN GEMM: ZT[o,i] = relu(sum_k W[o,k]*X[k,i] + b[o]).
// W = Wp (padded bf16, lda=K). X raw input (xn x xn), dual-mode, guarded.
// ---------------------------------------------------------------------------
__global__ __launch_bounds__(256, 2)
void gemm_nn_l0(const bf16* __restrict__ W, int lda,
                const void* __restrict__ X, int xn, const int* __restrict__ flag,
                const bf16* __restrict__ bias,
                bf16* __restrict__ ZT, int ldc, int K)
{
    __shared__ __align__(16) __bf16 As[128 * 32];   // W tile [o][k]
    __shared__ __bf16 Bs[32 * 128];                 // X tile [k][i]
    const int isbf = flag[0];
    const int tid  = threadIdx.x;
    const int wave = tid >> 6;
    const int lane = tid & 63;
    const int o0 = blockIdx.y * 128;
    const int i0 = blockIdx.x * 128;

    const int r0 = tid >> 2, r1 = r0 + 64, kc = (tid & 3) * 8;
    const bf16* gA0 = W + (size_t)(o0 + r0) * lda + kc;
    const bf16* gA1 = W + (size_t)(o0 + r1) * lda + kc;
    const int bk = tid >> 3;
    const int bi = (tid & 7) * 16;

    const int wm = (wave >> 1) * 64;
    const int wn = (wave & 1) * 64;
    const int fr = lane & 15;
    const int fk = (lane >> 4) * 8;

    f32x4 acc[4][4] = {};

    for (int kt = 0; kt < K; kt += 32) {
        bf16x8 a0 = *(const bf16x8*)(gA0 + kt);
        bf16x8 a1 = *(const bf16x8*)(gA1 + kt);
        float xv[16];
        const int gk = kt + bk;
        #pragma unroll
        for (int q = 0; q < 16; q++) {
            const int gi = i0 + bi + q;
            xv[q] = (gk < xn && gi < xn) ? rdv(X, (size_t)gk * xn + gi, isbf) : 0.f;
        }
        __syncthreads();
        *(bf16x8*)&As[r0 * 32 + kc] = a0;
        *(bf16x8*)&As[r1 * 32 + kc] = a1;
        #pragma unroll
        for (int q = 0; q < 16; q++) Bs[bk * 128 + bi + q] = (__bf16)xv[q];
        __syncthreads();

        bf16x8 af[4], bfv[4];
        #pragma unroll
        for (int t = 0; t < 4; t++)
            af[t] = *(const bf16x8*)&As[(wm + t * 16 + fr) * 32 + fk];
        #pragma unroll
        for (int nt = 0; nt < 4; nt++) {
            const int col = wn + nt * 16 + fr;
            #pragma unroll
            for (int j = 0; j < 8; j++)
                bfv[nt][j] = Bs[(fk + j) * 128 + col];
        }
        #pragma unroll
        for (int mt = 0; mt < 4; mt++)
            #pragma unroll
            for (int nt = 0; nt < 4; nt++)
                acc[mt][nt] = __builtin_amdgcn_mfma_f32_16x16x32_bf16(
                    af[mt], bfv[nt], acc[mt][nt], 0, 0, 0);
    }

    const int ci = (lane >> 4) * 4;
    const int cj = lane & 15;
    #pragma unroll
    for (int mt = 0; mt < 4; mt++) {
        #pragma unroll
        for (int rg = 0; rg < 4; rg++) {
            const int go = o0 + wm + mt * 16 + ci + rg;   // W row (M side)
            const float bv = (float)bias[go];
            #pragma unroll
            for (int nt = 0; nt < 4; nt++) {
                const int gi = i0 + wn + nt * 16 + cj;     // X col (N side)
                float v = acc[mt][nt][rg] + bv;
                v = v > 0.f ? v : 0.f;
                ZT[(size_t)go * ldc + gi] = (bf16)v;
            }
        }
    }
}

// dst (rp x cp) bf16 = src (r x c, dual-mode) zero-padded
__global__ void padcopy(const void* __restrict__ src, int r, int c,
                        bf16* __restrict__ dst, int rp, int cp,
                        const int* __restrict__ flag)
{
    const int isbf = flag[0];
    long idx = (long)blockIdx.x * 256 + threadIdx.x;
    if (idx >= (long)rp * cp) return;
    int i = (int)(idx / cp), j = (int)(idx % cp);
    float v = 0.f;
    if (i < r && j < c) v = rdv(src, (size_t)i * c + j, isbf);
    dst[idx] = (bf16)v;
}

__global__ void zero_f32(float* __restrict__ p, int n)
{
    int i = blockIdx.x * 256 + threadIdx.x;
    if (i < n) p[i] = 0.f;
}

// s[i] += sum_o Zt[o,i]*vt[oBase+o]; r likewise. Zt chunk-local (ld = nPad).
__global__ void scores_accum(const bf16* __restrict__ Zt, int ld,
                             int oBase, int oCount,
                             const void* __restrict__ vt, const void* __restrict__ vr,
                             float* __restrict__ s, float* __restrict__ r,
                             const int* __restrict__ flag)
{
    const int isbf = flag[0];
    const int i = blockIdx.x * 256 + threadIdx.x;
    const int o0 = blockIdx.y * 256;
    int o1 = o0 + 256; if (o1 > oCount) o1 = oCount;
    if (o0 >= o1) return;
    float as = 0.f, ar = 0.f;
    for (int o = o0; o < o1; o++) {
        float z = (float)Zt[(size_t)o * ld + i];
        as += z * rdv(vt, oBase + o, isbf);
        ar += z * rdv(vr, oBase + o, isbf);
    }
    atomicAdd(&s[i], as);
    atomicAdd(&r[i], ar);
}

__global__ void scores_bias(float* __restrict__ s, float* __restrict__ r,
                            const void* __restrict__ vtb, const void* __restrict__ vrb,
                            const int* __restrict__ flag)
{
    const int isbf = flag[0];
    int i = blockIdx.x * 256 + threadIdx.x;
    s[i] += rdv(vtb, 0, isbf);
    r[i] += rdv(vrb, 0, isbf);
}

// rowsum[i] = sum_{j<n} exp(sigmoid(A[i,j]*s[j] + A[j,i]*r[i]))
__global__ void rowsum_pass(const void* __restrict__ A, int n,
                            const float* __restrict__ s, const float* __restrict__ r,
                            float* __restrict__ rowsum, const int* __restrict__ flag)
{
    __shared__ float t2[32][33];
    const int isbf = flag[0];
    const int tx = threadIdx.x & 31;
    const int ty = threadIdx.x >> 5;
    const int i0 = blockIdx.y * 32;
    const int j0 = blockIdx.x * 32;
    #pragma unroll
    for (int q = 0; q < 4; q++) {        // stage A[j0+a][i0+tx]
        int jr = j0 + ty + q * 8;
        float v = 0.f;
        if (jr < n && i0 + tx < n) v = rdv(A, (size_t)jr * n + i0 + tx, isbf);
        t2[ty + q * 8][tx] = v;
    }
    __syncthreads();
    #pragma unroll
    for (int q = 0; q < 4; q++) {
        const int a  = ty + q * 8;
        const int gi = i0 + a;
        const int gj = j0 + tx;
        float e = 0.f;
        if (gi < n && gj < n) {
            float aij = rdv(A, (size_t)gi * n + gj, isbf);
            float x = aij * s[gj] + t2[tx][a] * r[gi];
            float sig = 1.f / (1.f + expf(-x));
            e = expf(sig);
        }
        float p = e;
        #pragma unroll
        for (int off = 16; off > 0; off >>= 1) p += __shfl_down(p, off, 32);
        if (tx == 0 && gi < n) atomicAdd(&rowsum[gi], p);
    }
}

// inv over ALL nPad rows; pad rows (rowsum==0) -> 0 (avoids poison reads).
__global__ void finalize_inv(const float* __restrict__ rowsum, float* __restrict__ inv, int nPad)
{
    int i = blockIdx.x * 256 + threadIdx.x;
    if (i < nPad) {
        float v = rowsum[i];
        inv[i] = v > 0.f ? 1.f / v : 0.f;
    }
}

// E-stripe: Estr[i-iOff][j] = e(i,j) for rows i in [iOff, iOff+SR), all j<nPad.
__global__ void e_stripe(const void* __restrict__ A, int n,
                         const float* __restrict__ s, const float* __restrict__ r,
                         bf16* __restrict__ Estr, int ldE, int iOff,
                         const int* __restrict__ flag)
{
    __shared__ float t2[32][33];
    const int isbf = flag[0];
    const int tx = threadIdx.x & 31;
    const int ty = threadIdx.x >> 5;
    const int i0 = iOff + blockIdx.y * 32;
    const int j0 = blockIdx.x * 32;
    #pragma unroll
    for (int q = 0; q < 4; q++) {
        int jr = j0 + ty + q * 8;
        float v = 0.f;
        if (jr < n && i0 + tx < n) v = rdv(A, (size_t)jr * n + i0 + tx, isbf);
        t2[ty + q * 8][tx] = v;
    }
    __syncthreads();
    #pragma unroll
    for (int q = 0; q < 4; q++) {
        const int a  = ty + q * 8;
        const int gi = i0 + a;
        const int gj = j0 + tx;
        float e = 0.f;
        if (gi < n && gj < n) {
            float aij = rdv(A, (size_t)gi * n + gj, isbf);
            float x = aij * s[gj] + t2[tx][a] * r[gi];
            float sig = 1.f / (1.f + expf(-x));
            e = expf(sig);
        }
        Estr[(size_t)(gi - iOff) * ldE + gj] = (bf16)e;
    }
}

// D (MP x 128): rows m<G from gG[c,m] (dual); rows G..M-1 from H3[m-G,c]; else 0
__global__ void build_D(const void* __restrict__ gG, const bf16* __restrict__ H3,
                        bf16* __restrict__ D, const int* __restrict__ flag)
{
    const int isbf = flag[0];
    int idx = blockIdx.x * 256 + threadIdx.x;
    int m = idx >> 7, c = idx & 127;
    float v = 0.f;
    if (c < 64) {
        if (m < N_GENES)      v = rdv(gG, (size_t)c * N_GENES + m, isbf);
        else if (m < M_NODES) v = (float)H3[(size_t)(m - N_GENES) * 128 + c];
    }
    D[idx] = (bf16)v;
}

extern "C" void kernel_launch(void* const* d_in, const int* in_sizes, int n_in,
                              void* d_out, int out_size, void* d_ws, size_t ws_size,
                              hipStream_t stream)
{
    const void* X     = d_in[0];
    const void* A_enc = d_in[1];
    const void* A_dec = d_in[2];
    const void* gG    = d_in[3];
    const void *W[7], *Wb[7], *vt[7], *vtb[7], *vr[7], *vrb[7];
    for (int l = 0; l < 7; l++) {
        W[l]   = d_in[4 + 6 * l + 0];
        Wb[l]  = d_in[4 + 6 * l + 1];
        vt[l]  = d_in[4 + 6 * l + 2];
        vtb[l] = d_in[4 + 6 * l + 3];
        vr[l]  = d_in[4 + 6 * l + 4];
        vrb[l] = d_in[4 + 6 * l + 5];
    }

    const int fop[7] = {512, 256, 128, 256, 512, 4096, 1024};
    const int fip[7] = {3072, 512, 256, 128, 256, 512, 512};
    const int foR[7] = {512, 256, 64, 256, 512, 4000, 1000};
    const int fiR[7] = {3000, 512, 256, 64, 256, 512, 512};

    // ---- workspace layout (~30.6 MB), small first ----
    char* ws = (char*)d_ws;
    size_t off = 0;
    auto alloc = [&](size_t bytes) -> void* {
        void* p = ws + off;
        off += (bytes + 255) & ~(size_t)255;
        return p;
    };
    int*   flag = (int*)alloc(256);
    float* sb   = (float*)alloc((size_t)MP * 4);
    float* rb   = (float*)alloc((size_t)MP * 4);
    float* rsum = (float*)alloc((size_t)MP * 4);
    float* rinv = (float*)alloc((size_t)MP * 4);
    bf16* Bp[7];
    for (int l = 0; l < 7; l++) Bp[l] = (bf16*)alloc((size_t)fop[l] * 2);
    bf16* RA = (bf16*)alloc((size_t)NP * 512 * 2);   // H1 -> H3 -> D1
    bf16* RB = (bf16*)alloc((size_t)NP * 256 * 2);   // H2 -> Dd
    bf16* RC = (bf16*)alloc((size_t)MP * 512 * 2);   // D2
    bf16 *H1 = RA, *H3 = RA, *D1 = RA;
    bf16 *H2 = RB, *Dd = RB;
    bf16 *D2 = RC;
    bf16* Wp[7];
    for (int l = 0; l < 7; l++) Wp[l] = (bf16*)alloc((size_t)fop[l] * fip[l] * 2);
    bf16* ZT   = (bf16*)alloc((size_t)CHMAX * MP * 2);
    bf16* Estr = (bf16*)alloc((size_t)SR * MP * 2);

    // ---- prep ----
    sniff_dtype<<<1, 256, 0, stream>>>((const unsigned int*)X, flag);
    for (int l = 0; l < 7; l++) {
        long tot = (long)fop[l] * fip[l];
        padcopy<<<dim3((unsigned)((tot + 255) / 256)), 256, 0, stream>>>(
            W[l], foR[l], fiR[l], Wp[l], fop[l], fip[l], flag);
        padcopy<<<dim3((fop[l] + 255) / 256), 256, 0, stream>>>(
            Wb[l], 1, foR[l], Bp[l], 1, fop[l], flag);
    }

    // OutT-generic layer driver
    auto layer = [&](const bf16* Hin, int l, const void* Araw,
                     int nReal, int nPad, auto* Hout, int ldOut, int mB, int nBtot) {
        const int K = fip[l], NO = fop[l];
        const int CH = NO > CHMAX ? CHMAX : NO;
        const int nch = NO / CH;
        const int nstr = nPad / SR;
        auto gemm1 = [&](int c) {
            if (l == 0)
                gemm_nn_l0<<<dim3(nPad / 128, NO / 128), 256, 0, stream>>>(
                    Wp[0], K, X, N_CELLS, flag, Bp[0], ZT, nPad, K);
            else
                gemm_nt<true, true, false, bf16><<<dim3(CH / 128, nPad / 128), 256, 0, stream>>>(
                    Hin, K, Wp[l] + (size_t)c * CH * K, K, Bp[l] + c * CH, nullptr,
                    ZT, nPad, K, nPad, CH, 0);
        };
        // pass A: scores
        zero_f32<<<dim3(nPad / 256), 256, 0, stream>>>(sb, nPad);
        zero_f32<<<dim3(nPad / 256), 256, 0, stream>>>(rb, nPad);
        for (int c = 0; c < nch; c++) {
            gemm1(c);
            int oBase = c * CH;
            int oCnt = foR[l] - oBase;
            if (oCnt > CH) oCnt = CH;
            if (oCnt > 0)
                scores_accum<<<dim3(nPad / 256, 4), 256, 0, stream>>>(
                    ZT, nPad, oBase, oCnt, vt[l], vr[l], sb, rb, flag);
        }
        scores_bias<<<dim3(nPad / 256), 256, 0, stream>>>(sb, rb, vtb[l], vrb[l], flag);
        // row sums -> inverses
        zero_f32<<<dim3(nPad / 256), 256, 0, stream>>>(rsum, nPad);
        rowsum_pass<<<dim3(nPad / 32, nPad / 32), 256, 0, stream>>>(Araw, nReal, sb, rb, rsum, flag);
        finalize_inv<<<dim3(nPad / 256), 256, 0, stream>>>(rsum, rinv, nPad);
        // pass B: Hout[iOff.., cols] = rinv * (E_stripe @ Z_chunk^T)
        for (int c = 0; c < nch; c++) {
            if (nch > 1) gemm1(c);   // ZT intact when nch==1
            int colBase = c * CH;
            int nB = nBtot - colBase;
            if (nB > CH) nB = CH;
            if (nB <= 0) continue;
            for (int st = 0; st < nstr; st++) {
                int iOff = st * SR;
                e_stripe<<<dim3(nPad / 32, SR / 32), 256, 0, stream>>>(
                    Araw, nReal, sb, rb, Estr, nPad, iOff, flag);
                gemm_nt<false, false, true><<<dim3(CH / 128, SR / 128), 256, 0, stream>>>(
                    Estr, nPad, ZT, nPad, nullptr, rinv,
                    Hout + colBase, ldOut, nPad, mB, nB, iOff);
            }
        }
    };

    // encoder (H0 = X^T handled inside gemm_nn_l0)
    layer(nullptr, 0, A_enc, N_CELLS, NP, H1, 512, NP, 512);
    layer(H1,      1, A_enc, N_CELLS, NP, H2, 256, NP, 256);
    layer(H2,      2, A_enc, N_CELLS, NP, H3, 128, NP, 128);
    // decoder input D = concat([gG, H3^T], axis=1)^T
    build_D<<<dim3((MP * 128) / 256), 256, 0, stream>>>(gG, H3, Dd, flag);
    layer(Dd, 3, A_dec, M_NODES, MP, D1, 256, MP, 256);
    layer(D1, 4, A_dec, M_NODES, MP, D2, 512, MP, 512);
    // FINAL OUTPUTS ARE FLOAT32 (reference dtype)
    float* outCell = (float*)d_out;
    float* outGene = outCell + (size_t)M_NODES * M_NODES;
    layer(D2, 5, A_dec, M_NODES, MP, outCell, 4000, 4000, 4000);
    layer(D2, 6, A_dec, M_NODES, MP, outGene, 1000, 4000, 1000);
}

// Round 6
// 3174.717 us; speedup vs baseline: 2.7763x; 2.7763x over previous
//
#include <hip/hip_runtime.h>
#include <hip/hip_bf16.h>

using bf16 = __hip_bfloat16;
typedef __bf16 bf16x8 __attribute__((ext_vector_type(8)));
typedef float f32x4 __attribute__((ext_vector_type(4)));

#define N_CELLS 3000
#define N_GENES 1000
#define M_NODES 4000
#define NP 3072
#define MP 4096
#define CHMAX 1024   // GEMM1 output-chunk columns

// dual-mode scalar read: inputs are f32 (sniffed) or bf16 (hedge)
__device__ __forceinline__ float rdv(const void* p, size_t i, int isbf) {
    if (isbf) return (float)((const bf16*)p)[i];
    return ((const float*)p)[i];
}

__device__ __forceinline__ void async_copy16(const bf16* g, bf16* l) {
    __builtin_amdgcn_global_load_lds((const __attribute__((address_space(1))) void*)g,
                                     (__attribute__((address_space(3))) void*)l,
                                     16, 0, 0);
}

// X ~ U[0,1): as bf16 every word's low16 < 0x3F80 (~100%); as f32 ~25%.
__global__ void sniff_dtype(const unsigned int* __restrict__ X, int* __restrict__ flag)
{
    __shared__ int cnt[4];
    int t = threadIdx.x;
    int c = 0;
    for (int i = t; i < 2048; i += 256)
        if ((X[i] & 0xFFFFu) < 0x3F80u) c++;
    #pragma unroll
    for (int off = 32; off > 0; off >>= 1) c += __shfl_down(c, off);
    if ((t & 63) == 0) cnt[t >> 6] = c;
    __syncthreads();
    if (t == 0) flag[0] = (cnt[0] + cnt[1] + cnt[2] + cnt[3] > 1536) ? 1 : 0;
}

// ---------------------------------------------------------------------------
// NT GEMM with async global->LDS staging (m97 pattern): C[i,j] =
// sum_k A[i,k]*B[j,k], 128x128 tile, K%32==0, bf16 in, OutT out.
// RELU_BIAS: C=relu(C+bias[j]). TRANS_OUT: store C[j,i]. SCALE_ROW: *rowinv[i].
// ---------------------------------------------------------------------------
template<bool RELU_BIAS, bool TRANS_OUT, bool SCALE_ROW, typename OutT>
__global__ __launch_bounds__(256, 2)
void gemm_nt(const bf16* __restrict__ A, int lda,
             const bf16* __restrict__ B, int ldb,
             const bf16* __restrict__ bias,
             const float* __restrict__ rowinv,
             OutT* __restrict__ C, int ldc,
             int K, int mBound, int nBound)
{
    __shared__ __align__(16) bf16 As[128 * 32];
    __shared__ __align__(16) bf16 Bs[128 * 32];
    const int tid  = threadIdx.x;
    const int wave = tid >> 6;
    const int lane = tid & 63;
    const int i0 = blockIdx.y * 128;
    const int j0 = blockIdx.x * 128;

    // async staging: wave w covers rows [w*32, w*32+32); lane -> (srow, 8-elem k)
    // HW writes lane i's 16B at (wave-uniform LDS base) + i*16 — layout matches.
    const int srow = lane >> 2;          // 0..15
    const int sk   = (lane & 3) * 8;     // 0,8,16,24
    const bf16* gA0 = A + (size_t)(i0 + wave * 32 + srow) * lda + sk;
    const bf16* gA1 = gA0 + (size_t)16 * lda;
    const bf16* gB0 = B + (size_t)(j0 + wave * 32 + srow) * ldb + sk;
    const bf16* gB1 = gB0 + (size_t)16 * ldb;
    bf16* lA0 = &As[(wave * 32) * 32];
    bf16* lA1 = &As[(wave * 32 + 16) * 32];
    bf16* lB0 = &Bs[(wave * 32) * 32];
    bf16* lB1 = &Bs[(wave * 32 + 16) * 32];

    const int wm = (wave >> 1) * 64;
    const int wn = (wave & 1) * 64;
    const int fr = lane & 15;
    const int fk = (lane >> 4) * 8;

    f32x4 acc[4][4] = {};

    for (int kt = 0; kt < K; kt += 32) {
        async_copy16(gA0 + kt, lA0);
        async_copy16(gA1 + kt, lA1);
        async_copy16(gB0 + kt, lB0);
        async_copy16(gB1 + kt, lB1);
        __syncthreads();   // drains vmcnt -> staged data visible

        bf16x8 af[4], bfv[4];
        #pragma unroll
        for (int t = 0; t < 4; t++) {
            af[t]  = *(const bf16x8*)&As[(wm + t * 16 + fr) * 32 + fk];
            bfv[t] = *(const bf16x8*)&Bs[(wn + t * 16 + fr) * 32 + fk];
        }
        #pragma unroll
        for (int mt = 0; mt < 4; mt++)
            #pragma unroll
            for (int nt = 0; nt < 4; nt++)
                acc[mt][nt] = __builtin_amdgcn_mfma_f32_16x16x32_bf16(
                    af[mt], bfv[nt], acc[mt][nt], 0, 0, 0);
        __syncthreads();   // all reads done before next stage overwrites
    }

    // C/D mapping: col(n)=lane&15, row(m)=(lane>>4)*4+reg
    const int ci = (lane >> 4) * 4;
    const int cj = lane & 15;
    #pragma unroll
    for (int nt = 0; nt < 4; nt++) {
        const int gj = j0 + wn + nt * 16 + cj;
        if (gj >= nBound) continue;
        float bv = 0.f;
        if (RELU_BIAS) bv = (float)bias[gj];
        #pragma unroll
        for (int mt = 0; mt < 4; mt++) {
            #pragma unroll
            for (int rg = 0; rg < 4; rg++) {
                const int gi = i0 + wm + mt * 16 + ci + rg;
                if (gi < mBound) {
                    float v = acc[mt][nt][rg];
                    if (RELU_BIAS) { v += bv; v = v > 0.f ? v : 0.f; }
                    if (SCALE_ROW) v *= rowinv[gi];
                    if (TRANS_OUT) C[(size_t)gj * ldc + gi] = (OutT)v;
                    else           C[(size_t)gi * ldc + gj] = (OutT)v;
                }
            }
        }
    }
}

// ---------------------------------------------------------------------------
// Layer-0 NN GEMM: ZT[o,i] = relu(sum_k W[o,k]*X[k,i] + b[o]).
// W padded bf16 (lda=K); X raw dual-mode (xn x xn), guarded.
// ---------------------------------------------------------------------------
__global__ __launch_bounds__(256, 2)
void gemm_nn_l0(const bf16* __restrict__ W, int lda,
                const void* __restrict__ X, int xn, const int* __restrict__ flag,
                const bf16* __restrict__ bias,
                bf16* __restrict__ ZT, int ldc, int K)
{
    __shared__ __align__(16) __bf16 As[128 * 32];   // W tile [o][k]
    __shared__ __bf16 Bs[32 * 128];                 // X tile [k][i]
    const int isbf = flag[0];
    const int tid  = threadIdx.x;
    const int wave = tid >> 6;
    const int lane = tid & 63;
    const int o0 = blockIdx.y * 128;
    const int i0 = blockIdx.x * 128;

    const int r0 = tid >> 2, r1 = r0 + 64, kc = (tid & 3) * 8;
    const bf16* gA0 = W + (size_t)(o0 + r0) * lda + kc;
    const bf16* gA1 = W + (size_t)(o0 + r1) * lda + kc;
    const int bk = tid >> 3;
    const int bi = (tid & 7) * 16;

    const int wm = (wave >> 1) * 64;
    const int wn = (wave & 1) * 64;
    const int fr = lane & 15;
    const int fk = (lane >> 4) * 8;

    f32x4 acc[4][4] = {};

    for (int kt = 0; kt < K; kt += 32) {
        bf16x8 a0 = *(const bf16x8*)(gA0 + kt);
        bf16x8 a1 = *(const bf16x8*)(gA1 + kt);
        float xv[16];
        const int gk = kt + bk;
        #pragma unroll
        for (int q = 0; q < 16; q++) {
            const int gi = i0 + bi + q;
            xv[q] = (gk < xn && gi < xn) ? rdv(X, (size_t)gk * xn + gi, isbf) : 0.f;
        }
        __syncthreads();
        *(bf16x8*)&As[r0 * 32 + kc] = a0;
        *(bf16x8*)&As[r1 * 32 + kc] = a1;
        #pragma unroll
        for (int q = 0; q < 16; q++) Bs[bk * 128 + bi + q] = (__bf16)xv[q];
        __syncthreads();

        bf16x8 af[4], bfv[4];
        #pragma unroll
        for (int t = 0; t < 4; t++)
            af[t] = *(const bf16x8*)&As[(wm + t * 16 + fr) * 32 + fk];
        #pragma unroll
        for (int nt = 0; nt < 4; nt++) {
            const int col = wn + nt * 16 + fr;
            #pragma unroll
            for (int j = 0; j < 8; j++)
                bfv[nt][j] = Bs[(fk + j) * 128 + col];
        }
        #pragma unroll
        for (int mt = 0; mt < 4; mt++)
            #pragma unroll
            for (int nt = 0; nt < 4; nt++)
                acc[mt][nt] = __builtin_amdgcn_mfma_f32_16x16x32_bf16(
                    af[mt], bfv[nt], acc[mt][nt], 0, 0, 0);
        __syncthreads();
    }

    const int ci = (lane >> 4) * 4;
    const int cj = lane & 15;
    #pragma unroll
    for (int mt = 0; mt < 4; mt++) {
        #pragma unroll
        for (int rg = 0; rg < 4; rg++) {
            const int go = o0 + wm + mt * 16 + ci + rg;
            const float bv = (float)bias[go];
            #pragma unroll
            for (int nt = 0; nt < 4; nt++) {
                const int gi = i0 + wn + nt * 16 + cj;
                float v = acc[mt][nt][rg] + bv;
                v = v > 0.f ? v : 0.f;
                ZT[(size_t)go * ldc + gi] = (bf16)v;
            }
        }
    }
}

// dst (rp x cp) bf16 = src (r x c, dual-mode) zero-padded
__global__ void padcopy(const void* __restrict__ src, int r, int c,
                        bf16* __restrict__ dst, int rp, int cp,
                        const int* __restrict__ flag)
{
    const int isbf = flag[0];
    long idx = (long)blockIdx.x * 256 + threadIdx.x;
    if (idx >= (long)rp * cp) return;
    int i = (int)(idx / cp), j = (int)(idx % cp);
    float v = 0.f;
    if (i < r && j < c) v = rdv(src, (size_t)i * c + j, isbf);
    dst[idx] = (bf16)v;
}

__global__ void zero_f32(float* __restrict__ p, int n)
{
    int i = blockIdx.x * 256 + threadIdx.x;
    if (i < n) p[i] = 0.f;
}

// s[i] += sum_o Zt[o,i]*vt[oBase+o]; r likewise. Zt chunk-local (ld = nPad).
__global__ void scores_accum(const bf16* __restrict__ Zt, int ld,
                             int oBase, int oCount,
                             const void* __restrict__ vt, const void* __restrict__ vr,
                             float* __restrict__ s, float* __restrict__ r,
                             const int* __restrict__ flag)
{
    const int isbf = flag[0];
    const int i = blockIdx.x * 256 + threadIdx.x;
    const int o0 = blockIdx.y * 256;
    int o1 = o0 + 256; if (o1 > oCount) o1 = oCount;
    if (o0 >= o1) return;
    float as = 0.f, ar = 0.f;
    for (int o = o0; o < o1; o++) {
        float z = (float)Zt[(size_t)o * ld + i];
        as += z * rdv(vt, oBase + o, isbf);
        ar += z * rdv(vr, oBase + o, isbf);
    }
    atomicAdd(&s[i], as);
    atomicAdd(&r[i], ar);
}

__global__ void scores_bias(float* __restrict__ s, float* __restrict__ r,
                            const void* __restrict__ vtb, const void* __restrict__ vrb,
                            const int* __restrict__ flag)
{
    const int isbf = flag[0];
    int i = blockIdx.x * 256 + threadIdx.x;
    s[i] += rdv(vtb, 0, isbf);
    r[i] += rdv(vrb, 0, isbf);
}

// Full E: E[i,j] = exp(sigmoid(A[i,j]*s[j] + A[j,i]*r[i])) (i,j<n else 0),
// all nPad x nPad written; fp32 row sums accumulated via per-tile atomics.
__global__ void e_pass(const void* __restrict__ A, int n,
                       const float* __restrict__ s, const float* __restrict__ r,
                       bf16* __restrict__ E, int ldE, float* __restrict__ rowsum,
                       const int* __restrict__ flag)
{
    __shared__ float t2[32][33];
    const int isbf = flag[0];
    const int tx = threadIdx.x & 31;
    const int ty = threadIdx.x >> 5;
    const int i0 = blockIdx.y * 32;
    const int j0 = blockIdx.x * 32;
    #pragma unroll
    for (int q = 0; q < 4; q++) {        // stage A[j0+a][i0+tx] (transposed access)
        int jr = j0 + ty + q * 8;
        float v = 0.f;
        if (jr < n && i0 + tx < n) v = rdv(A, (size_t)jr * n + i0 + tx, isbf);
        t2[ty + q * 8][tx] = v;
    }
    __syncthreads();
    #pragma unroll
    for (int q = 0; q < 4; q++) {
        const int a  = ty + q * 8;
        const int gi = i0 + a;
        const int gj = j0 + tx;
        float e = 0.f;
        if (gi < n && gj < n) {
            float aij = rdv(A, (size_t)gi * n + gj, isbf);
            float x = aij * s[gj] + t2[tx][a] * r[gi];
            float sig = 1.f / (1.f + expf(-x));
            e = expf(sig);
        }
        E[(size_t)gi * ldE + gj] = (bf16)e;
        float p = e;
        #pragma unroll
        for (int off = 16; off > 0; off >>= 1) p += __shfl_down(p, off, 32);
        if (tx == 0 && gi < n) atomicAdd(&rowsum[gi], p);
    }
}

// inv over ALL nPad rows; pad rows (rowsum==0) -> 0.
__global__ void finalize_inv(const float* __restrict__ rowsum, float* __restrict__ inv, int nPad)
{
    int i = blockIdx.x * 256 + threadIdx.x;
    if (i < nPad) {
        float v = rowsum[i];
        inv[i] = v > 0.f ? 1.f / v : 0.f;
    }
}

// D (MP x 128): rows m<G from gG[c,m] (dual); rows G..M-1 from H3[m-G,c]; else 0
__global__ void build_D(const void* __restrict__ gG, const bf16* __restrict__ H3,
                        bf16* __restrict__ D, const int* __restrict__ flag)
{
    const int isbf = flag[0];
    int idx = blockIdx.x * 256 + threadIdx.x;
    int m = idx >> 7, c = idx & 127;
    float v = 0.f;
    if (c < 64) {
        if (m < N_GENES)      v = rdv(gG, (size_t)c * N_GENES + m, isbf);
        else if (m < M_NODES) v = (float)H3[(size_t)(m - N_GENES) * 128 + c];
    }
    D[idx] = (bf16)v;
}

extern "C" void kernel_launch(void* const* d_in, const int* in_sizes, int n_in,
                              void* d_out, int out_size, void* d_ws, size_t ws_size,
                              hipStream_t stream)
{
    const void* X     = d_in[0];
    const void* A_enc = d_in[1];
    const void* A_dec = d_in[2];
    const void* gG    = d_in[3];
    const void *W[7], *Wb[7], *vt[7], *vtb[7], *vr[7], *vrb[7];
    for (int l = 0; l < 7; l++) {
        W[l]   = d_in[4 + 6 * l + 0];
        Wb[l]  = d_in[4 + 6 * l + 1];
        vt[l]  = d_in[4 + 6 * l + 2];
        vtb[l] = d_in[4 + 6 * l + 3];
        vr[l]  = d_in[4 + 6 * l + 4];
        vrb[l] = d_in[4 + 6 * l + 5];
    }

    const int fop[7] = {512, 256, 128, 256, 512, 4096, 1024};
    const int fip[7] = {3072, 512, 256, 128, 256, 512, 512};
    const int foR[7] = {512, 256, 64, 256, 512, 4000, 1000};
    const int fiR[7] = {3000, 512, 256, 64, 256, 512, 512};

    // ---- workspace layout (~59 MB), small first ----
    char* ws = (char*)d_ws;
    size_t off = 0;
    auto alloc = [&](size_t bytes) -> void* {
        void* p = ws + off;
        off += (bytes + 255) & ~(size_t)255;
        return p;
    };
    int*   flag = (int*)alloc(256);
    float* sb   = (float*)alloc((size_t)MP * 4);   // sb, rb, rsum contiguous
    float* rb   = (float*)alloc((size_t)MP * 4);
    float* rsum = (float*)alloc((size_t)MP * 4);
    float* rinv = (float*)alloc((size_t)MP * 4);
    bf16* Bp[7];
    for (int l = 0; l < 7; l++) Bp[l] = (bf16*)alloc((size_t)fop[l] * 2);
    bf16* RA = (bf16*)alloc((size_t)NP * 512 * 2);   // H1 -> H3 -> D1
    bf16* RB = (bf16*)alloc((size_t)NP * 256 * 2);   // H2 -> Dd
    bf16* RC = (bf16*)alloc((size_t)MP * 512 * 2);   // D2
    bf16 *H1 = RA, *H3 = RA, *D1 = RA;
    bf16 *H2 = RB, *Dd = RB;
    bf16 *D2 = RC;
    bf16* Wp[7];
    for (int l = 0; l < 7; l++) Wp[l] = (bf16*)alloc((size_t)fop[l] * fip[l] * 2);
    bf16* ZT = (bf16*)alloc((size_t)CHMAX * MP * 2);   // 8 MB
    bf16* E  = (bf16*)alloc((size_t)MP * MP * 2);      // 32 MB

    // ---- prep ----
    sniff_dtype<<<1, 256, 0, stream>>>((const unsigned int*)X, flag);
    for (int l = 0; l < 7; l++) {
        long tot = (long)fop[l] * fip[l];
        padcopy<<<dim3((unsigned)((tot + 255) / 256)), 256, 0, stream>>>(
            W[l], foR[l], fiR[l], Wp[l], fop[l], fip[l], flag);
        padcopy<<<dim3((fop[l] + 255) / 256), 256, 0, stream>>>(
            Wb[l], 1, foR[l], Bp[l], 1, fop[l], flag);
    }

    auto layer = [&](const bf16* Hin, int l, const void* Araw,
                     int nReal, int nPad, auto* Hout, int ldOut, int mB, int nBtot) {
        const int K = fip[l], NO = fop[l];
        const int CH = NO > CHMAX ? CHMAX : NO;
        const int nch = NO / CH;
        auto gemm1 = [&](int c) {
            if (l == 0)
                gemm_nn_l0<<<dim3(nPad / 128, NO / 128), 256, 0, stream>>>(
                    Wp[0], K, X, N_CELLS, flag, Bp[0], ZT, nPad, K);
            else
                gemm_nt<true, true, false, bf16><<<dim3(CH / 128, nPad / 128), 256, 0, stream>>>(
                    Hin, K, Wp[l] + (size_t)c * CH * K, K, Bp[l] + c * CH, nullptr,
                    ZT, nPad, K, nPad, CH);
        };
        // pass A: scores (sb, rb, rsum zeroed in one launch — contiguous)
        zero_f32<<<dim3(3 * MP / 256), 256, 0, stream>>>(sb, 3 * MP);
        for (int c = 0; c < nch; c++) {
            gemm1(c);
            int oBase = c * CH;
            int oCnt = foR[l] - oBase;
            if (oCnt > CH) oCnt = CH;
            if (oCnt > 0)
                scores_accum<<<dim3(nPad / 256, 4), 256, 0, stream>>>(
                    ZT, nPad, oBase, oCnt, vt[l], vr[l], sb, rb, flag);
        }
        scores_bias<<<dim3(nPad / 256), 256, 0, stream>>>(sb, rb, vtb[l], vrb[l], flag);
        // full E + row sums (once per layer)
        e_pass<<<dim3(nPad / 32, nPad / 32), 256, 0, stream>>>(
            Araw, nReal, sb, rb, E, nPad, rsum, flag);
        finalize_inv<<<dim3(nPad / 256), 256, 0, stream>>>(rsum, rinv, nPad);
        // pass B: Hout[:, cols] = rinv[i] * (E @ Z_chunk^T), full row grid
        for (int c = 0; c < nch; c++) {
            if (nch > 1) gemm1(c);   // ZT intact when nch==1
            int colBase = c * CH;
            int nB = nBtot - colBase;
            if (nB > CH) nB = CH;
            if (nB <= 0) continue;
            gemm_nt<false, false, true><<<dim3(CH / 128, nPad / 128), 256, 0, stream>>>(
                E, nPad, ZT, nPad, nullptr, rinv,
                Hout + colBase, ldOut, nPad, mB, nB);
        }
    };

    // encoder (H0 = X^T handled inside gemm_nn_l0)
    layer(nullptr, 0, A_enc, N_CELLS, NP, H1, 512, NP, 512);
    layer(H1,      1, A_enc, N_CELLS, NP, H2, 256, NP, 256);
    layer(H2,      2, A_enc, N_CELLS, NP, H3, 128, NP, 128);
    // decoder input D = concat([gG, H3^T], axis=1)^T
    build_D<<<dim3((MP * 128) / 256), 256, 0, stream>>>(gG, H3, Dd, flag);
    layer(Dd, 3, A_dec, M_NODES, MP, D1, 256, MP, 256);
    layer(D1, 4, A_dec, M_NODES, MP, D2, 512, MP, 512);
    // outputs are float32 (reference dtype)
    float* outCell = (float*)d_out;
    float* outGene = outCell + (size_t)M_NODES * M_NODES;
    layer(D2, 5, A_dec, M_NODES, MP, outCell, 4000, 4000, 4000);
    layer(D2, 6, A_dec, M_NODES, MP, outGene, 1000, 4000, 1000);
}